// Round 1
// baseline (33.211 us; speedup 1.0000x reference)
//
#include <hip/hip_runtime.h>

#define NN 4096
#define MM 4096
#define PP 32

// ---------------------------------------------------------------------------
// Kernel A: row norms.  ws[0..NN) = ||x1_i||^2, ws[NN..NN+MM) = ||x2_j||^2
// (raw norms; rho scaling folded into the epilogue of kernel B)
// ---------------------------------------------------------------------------
__global__ void eq_norms_kernel(const float* __restrict__ x1,
                                const float* __restrict__ x2,
                                float* __restrict__ ws) {
    int t = blockIdx.x * blockDim.x + threadIdx.x;  // 0 .. NN+MM-1
    if (t >= NN + MM) return;
    const float* src = (t < NN) ? x1 : x2;
    int row = (t < NN) ? t : t - NN;
    const float4* p4 = reinterpret_cast<const float4*>(src + row * PP);
    float s = 0.f;
#pragma unroll
    for (int k = 0; k < PP / 4; ++k) {
        float4 v = p4[k];
        s = fmaf(v.x, v.x, s);
        s = fmaf(v.y, v.y, s);
        s = fmaf(v.z, v.z, s);
        s = fmaf(v.w, v.w, s);
    }
    ws[t] = s;
}

// ---------------------------------------------------------------------------
// Kernel B: 64x64 output tile per 256-thread block, 4x4 register accumulation.
// d = (xn + yn - 2*dot) * inv_rho^2 ; K = sigma * exp(-0.5*d)
// LDS tiles stored p-major [32][68]: pad 68 -> row byte offset p*272 is
// 16B-aligned (ds_read_b128 ok) and spreads banks (p*4+row mod 32).
// ---------------------------------------------------------------------------
__launch_bounds__(256)
__global__ void eq_main_kernel(const float* __restrict__ x1,
                               const float* __restrict__ x2,
                               const float* __restrict__ log_rho,
                               const float* __restrict__ log_sigma,
                               const float* __restrict__ norms,
                               float* __restrict__ out) {
    __shared__ float As[PP][68];
    __shared__ float Bs[PP][68];

    const int bx = blockIdx.x;  // col tile (x2 rows)
    const int by = blockIdx.y;  // row tile (x1 rows)
    const int t  = threadIdx.x;

    // Stage 64x32 tiles of x1 and x2 into LDS, transposed to p-major.
    // idx = t + k*256 walks the tile linearly -> global loads fully coalesced.
#pragma unroll
    for (int k = 0; k < 8; ++k) {
        int idx = t + k * 256;
        int row = idx >> 5;   // 0..63
        int p   = idx & 31;   // 0..31
        As[p][row] = x1[(by * 64 + row) * PP + p];
        Bs[p][row] = x2[(bx * 64 + row) * PP + p];
    }
    __syncthreads();

    const int tx = t & 15;   // 0..15 -> 4 output cols each
    const int ty = t >> 4;   // 0..15 -> 4 output rows each

    float acc[4][4] = {};
#pragma unroll
    for (int p = 0; p < PP; ++p) {
        float4 a4 = *reinterpret_cast<const float4*>(&As[p][ty * 4]);
        float4 b4 = *reinterpret_cast<const float4*>(&Bs[p][tx * 4]);
        float av[4] = {a4.x, a4.y, a4.z, a4.w};
        float bv[4] = {b4.x, b4.y, b4.z, b4.w};
#pragma unroll
        for (int i = 0; i < 4; ++i)
#pragma unroll
            for (int j = 0; j < 4; ++j)
                acc[i][j] = fmaf(av[i], bv[j], acc[i][j]);
    }

    // epilogue scalars (tiny, L2-cached reads; uniform across all threads)
    const float inv_rho  = __expf(-log_rho[0]);
    const float inv_rho2 = inv_rho * inv_rho;
    const float sigma    = __expf(2.f * log_sigma[0]);

    float xn[4], yn[4];
#pragma unroll
    for (int i = 0; i < 4; ++i) xn[i] = norms[by * 64 + ty * 4 + i];
#pragma unroll
    for (int j = 0; j < 4; ++j) yn[j] = norms[NN + bx * 64 + tx * 4 + j];

#pragma unroll
    for (int i = 0; i < 4; ++i) {
        float r[4];
#pragma unroll
        for (int j = 0; j < 4; ++j) {
            float d = fmaf(-2.f, acc[i][j], xn[i] + yn[j]) * inv_rho2;
            d = fmaxf(d, 0.f);
            r[j] = sigma * __expf(-0.5f * d);
        }
        float4 o = {r[0], r[1], r[2], r[3]};
        int row = by * 64 + ty * 4 + i;
        int col = bx * 64 + tx * 4;
        *reinterpret_cast<float4*>(&out[row * MM + col]) = o;
    }
}

extern "C" void kernel_launch(void* const* d_in, const int* in_sizes, int n_in,
                              void* d_out, int out_size, void* d_ws, size_t ws_size,
                              hipStream_t stream) {
    const float* x1        = (const float*)d_in[0];
    const float* x2        = (const float*)d_in[1];
    const float* log_rho   = (const float*)d_in[2];
    const float* log_sigma = (const float*)d_in[3];
    float* out = (float*)d_out;
    float* ws  = (float*)d_ws;   // NN+MM floats of scratch for norms

    eq_norms_kernel<<<(NN + MM + 255) / 256, 256, 0, stream>>>(x1, x2, ws);

    dim3 grid(MM / 64, NN / 64);
    eq_main_kernel<<<grid, 256, 0, stream>>>(x1, x2, log_rho, log_sigma, ws, out);
}

// Round 2
// 28.498 us; speedup vs baseline: 1.1654x; 1.1654x over previous
//
#include <hip/hip_runtime.h>

#define NN 4096
#define MM 4096
#define PP 32

// Single fused kernel: 128x128 output tile per 256-thread block, 8x8 microtile.
// - Stage x1/x2 tiles into LDS transposed to p-major [32][132] (pad 132 ->
//   row byte offset p*528 is 16B aligned; staging writes spread banks 4-way).
// - Row norms computed in-tile (P=32 fits entirely in the tile).
// - d = (xn + yn - 2*dot) * inv_rho^2 ; K = sigma * exp(-0.5*d)
__launch_bounds__(256, 4)
__global__ void eq_fused_kernel(const float* __restrict__ x1,
                                const float* __restrict__ x2,
                                const float* __restrict__ log_rho,
                                const float* __restrict__ log_sigma,
                                float* __restrict__ out) {
    __shared__ float As[PP][132];
    __shared__ float Bs[PP][132];
    __shared__ float xn_s[128];
    __shared__ float yn_s[128];

    const int bx = blockIdx.x;  // col tile (x2 rows)
    const int by = blockIdx.y;  // row tile (x1 rows)
    const int t  = threadIdx.x;

    // Stage 128x32 tiles, coalesced global reads, transposed LDS writes.
#pragma unroll
    for (int k = 0; k < 16; ++k) {
        int idx = t + k * 256;
        int row = idx >> 5;   // 0..127
        int p   = idx & 31;   // 0..31
        As[p][row] = x1[(by * 128 + row) * PP + p];
        Bs[p][row] = x2[(bx * 128 + row) * PP + p];
    }
    __syncthreads();

    // In-tile row norms: waves 0-1 do xn, waves 2-3 do yn (wave-uniform branch).
    // Bank pattern: fixed p, row varies across lanes -> 2 lanes/bank (free).
    if (t < 128) {
        float s = 0.f;
#pragma unroll
        for (int p = 0; p < PP; ++p) s = fmaf(As[p][t], As[p][t], s);
        xn_s[t] = s;
    } else {
        int r = t - 128;
        float s = 0.f;
#pragma unroll
        for (int p = 0; p < PP; ++p) s = fmaf(Bs[p][r], Bs[p][r], s);
        yn_s[r] = s;
    }
    __syncthreads();

    const int tx = t & 15;   // 0..15 -> 8 output cols each
    const int ty = t >> 4;   // 0..15 -> 8 output rows each

    float acc[8][8] = {};
#pragma unroll 4
    for (int p = 0; p < PP; ++p) {
        float4 a0 = *reinterpret_cast<const float4*>(&As[p][ty * 8]);
        float4 a1 = *reinterpret_cast<const float4*>(&As[p][ty * 8 + 4]);
        float4 b0 = *reinterpret_cast<const float4*>(&Bs[p][tx * 8]);
        float4 b1 = *reinterpret_cast<const float4*>(&Bs[p][tx * 8 + 4]);
        float av[8] = {a0.x, a0.y, a0.z, a0.w, a1.x, a1.y, a1.z, a1.w};
        float bv[8] = {b0.x, b0.y, b0.z, b0.w, b1.x, b1.y, b1.z, b1.w};
#pragma unroll
        for (int i = 0; i < 8; ++i)
#pragma unroll
            for (int j = 0; j < 8; ++j)
                acc[i][j] = fmaf(av[i], bv[j], acc[i][j]);
    }

    // Epilogue
    const float inv_rho2 = __expf(-2.f * log_rho[0]);
    const float sigma    = __expf(2.f * log_sigma[0]);

    float yn[8];
#pragma unroll
    for (int j = 0; j < 8; ++j) yn[j] = yn_s[tx * 8 + j];

    const int col = bx * 128 + tx * 8;
#pragma unroll
    for (int i = 0; i < 8; ++i) {
        const float xn = xn_s[ty * 8 + i];
        float r[8];
#pragma unroll
        for (int j = 0; j < 8; ++j) {
            float d = fmaf(-2.f, acc[i][j], xn + yn[j]) * inv_rho2;
            d = fmaxf(d, 0.f);
            r[j] = sigma * __expf(-0.5f * d);
        }
        const int row = by * 128 + ty * 8 + i;
        float4 o0 = {r[0], r[1], r[2], r[3]};
        float4 o1 = {r[4], r[5], r[6], r[7]};
        *reinterpret_cast<float4*>(&out[row * MM + col])     = o0;
        *reinterpret_cast<float4*>(&out[row * MM + col + 4]) = o1;
    }
}

extern "C" void kernel_launch(void* const* d_in, const int* in_sizes, int n_in,
                              void* d_out, int out_size, void* d_ws, size_t ws_size,
                              hipStream_t stream) {
    const float* x1        = (const float*)d_in[0];
    const float* x2        = (const float*)d_in[1];
    const float* log_rho   = (const float*)d_in[2];
    const float* log_sigma = (const float*)d_in[3];
    float* out = (float*)d_out;

    dim3 grid(MM / 128, NN / 128);
    eq_fused_kernel<<<grid, 256, 0, stream>>>(x1, x2, log_rho, log_sigma, out);
}